// Round 2
// baseline (208.581 us; speedup 1.0000x reference)
//
#include <hip/hip_runtime.h>
#include <math.h>

#define BATCH 64
#define HH 512
#define WW 512
#define KRAD 15
#define KSZ 31
#define NTOT ((size_t)BATCH * HH * WW)
#define TILE_Y 64
#define NCHUNK (HH / TILE_Y)            // 8
#define NBLK (BATCH * NCHUNK)           // 512 blocks
#define RING 64                         // fp16 prefix ring rows (64 KB, &63 free)

typedef _Float16 h8 __attribute__((ext_vector_type(8)));

// Wave64 inclusive add-scan via DPP (LLVM AMDGPUAtomicOptimizer sequence).
// Pure VALU: zero LDS-pipe traffic.
__device__ __forceinline__ float dpp_scan_add(float v) {
    int t;
    t = __builtin_amdgcn_update_dpp(0, __float_as_int(v), 0x111, 0xf, 0xf, false); // row_shr:1
    v += __int_as_float(t);
    t = __builtin_amdgcn_update_dpp(0, __float_as_int(v), 0x112, 0xf, 0xf, false); // row_shr:2
    v += __int_as_float(t);
    t = __builtin_amdgcn_update_dpp(0, __float_as_int(v), 0x114, 0xf, 0xf, false); // row_shr:4
    v += __int_as_float(t);
    t = __builtin_amdgcn_update_dpp(0, __float_as_int(v), 0x118, 0xf, 0xf, false); // row_shr:8
    v += __int_as_float(t);
    t = __builtin_amdgcn_update_dpp(0, __float_as_int(v), 0x142, 0xa, 0xf, false); // row_bcast:15 -> rows 1,3
    v += __int_as_float(t);
    t = __builtin_amdgcn_update_dpp(0, __float_as_int(v), 0x143, 0xc, 0xf, false); // row_bcast:31 -> rows 2,3
    v += __int_as_float(t);
    return v;
}

// ---------------------------------------------------------------------------
// TILE_Y=64, 64-row fp16 PREFIX ring, two whole-block phases, and now ALL
// 1024 threads compute: each column x is split between two threads
// (half = tid>>9), each owning 16 rows per phase.
//   scan rel 0..61 -> B -> compute rows 0..31 (half0: 0..15, half1: 16..31)
//   -> B -> scan rel 62..93 (slots 62,63,0..29; live 30..61 untouched)
//   -> B -> compute rows 32..63 (half0: 32..47, half1: 48..63).
// Each 16-row strip re-inits its own 31-row window (4-way partial sums,
// reads batchable), then materializes vs[16] (static-indexed) so the
// fully-unrolled loss loop has no LDS on its critical path.
// ---------------------------------------------------------------------------
__global__ __launch_bounds__(1024, 8) void mega_kernel(const float* __restrict__ logits,
                                                       const float* __restrict__ targ,
                                                       float* __restrict__ pbuf) {
    __shared__ _Float16 Pring[RING * WW];   // 64 KB
    __shared__ float red[3][16];

    const int b     = blockIdx.x >> 3;          // batch
    const int chunk = blockIdx.x & (NCHUNK - 1);
    const int y0    = chunk * TILE_Y;

    const int wave = threadIdx.x >> 6;          // 0..15
    const int lane = threadIdx.x & 63;

    // Scan one row (rel = y_abs-(y0-15)): store fp16 PREFIX into slot rel&63.
    // Zero-writes out-of-range rows (zero-pad semantics).
    auto scan_row = [&](int rel) {
        const int y_abs = y0 - KRAD + rel;
        h8 hv = {};
        if (y_abs >= 0 && y_abs < HH) {
            const float4* rp = (const float4*)(targ + ((size_t)b * HH + y_abs) * WW);
            float4 a  = rp[2 * lane];
            float4 b4 = rp[2 * lane + 1];
            float v[8] = {a.x, a.y, a.z, a.w, b4.x, b4.y, b4.z, b4.w};

            float T = 0.0f;
            float P[8];
#pragma unroll
            for (int j = 0; j < 8; ++j) { T += v[j]; P[j] = T; }

            const float incl = dpp_scan_add(T);
            const float excl = incl - T;
#pragma unroll
            for (int j = 0; j < 8; ++j) hv[j] = (_Float16)(P[j] + excl);
        }
        *(h8*)&Pring[(rel & (RING - 1)) * WW + lane * 8] = hv;
    };

    // ---- Phase A scan: rel 0..61 (slots 0..61) ----
#pragma unroll
    for (int i = 0; i < 4; ++i) {
        const int rel = wave + 16 * i;
        if (rel < 62) scan_row(rel);
    }
    __syncthreads();

    // ---- Compute setup: ALL threads. Column x, vertical half. ----
    const int x    = threadIdx.x & (WW - 1);    // 0..511
    const int half = threadIdx.x >> 9;          // 0 or 1
    const float* Tp = targ   + ((size_t)b * HH + y0) * WW + x;
    const float* Lp = logits + ((size_t)b * HH + y0) * WW + x;
    const float inv_ksq = 1.0f / (float)(KSZ * KSZ);
    float a_wbce = 0.0f, a_int = 0.0f, a_tot = 0.0f;

    const int  xa     = (x + KRAD > WW - 1) ? (WW - 1) : (x + KRAD);
    const int  xbc    = (x - KRAD - 1 < 0) ? 0 : (x - KRAD - 1);
    const bool has_lo = (x >= KRAD + 1);

    // H(rel, x) from the prefix ring (2 conflict-free u16 reads)
    auto Hval = [&](int rel) -> float {
        const _Float16* row = &Pring[(rel & (RING - 1)) * WW];
        const float hi = (float)row[xa];
        float lo = (float)row[xbc];
        lo = has_lo ? lo : 0.0f;
        return hi - lo;
    };

    // One 16-row strip starting at absolute row ys (window rel = ys..ys+30
    // for the first row; all ring slots proven live for each phase/half).
    auto do16 = [&](int ys) {
        // init: 31 H rows, 4-way partial sums (independent, batchable reads)
        float s0 = 0.0f, s1 = 0.0f, s2 = 0.0f, s3 = 0.0f;
#pragma unroll
        for (int r = 0; r < 28; r += 4) {
            s0 += Hval(ys + r);
            s1 += Hval(ys + r + 1);
            s2 += Hval(ys + r + 2);
            s3 += Hval(ys + r + 3);
        }
        s0 += Hval(ys + 28);
        s1 += Hval(ys + 29);
        s2 += Hval(ys + 30);

        float vs[16];
        vs[0] = (s0 + s1) + (s2 + s3);
#pragma unroll
        for (int j = 1; j < 16; ++j)
            vs[j] = vs[j - 1] + (Hval(ys + j + 30) - Hval(ys + j - 1));

#pragma unroll
        for (int j = 0; j < 16; ++j) {
            const int y = ys + j;
            const float s = vs[j] * inv_ksq;
            const float t = Tp[(size_t)y * WW];
            const float L = __builtin_nontemporal_load(Lp + (size_t)y * WW);

            const float weit = 1.0f + 5.0f * fabsf(s - t);
            const float e  = __expf(-fabsf(L));
            const float r  = __builtin_amdgcn_rcpf(1.0f + e);
            const float lg = __logf(1.0f + e);          // softplus(-|L|)
            const float sp  = fmaxf(L, 0.0f) + lg;      // softplus(L)
            const float bce = sp - t * L;
            const float p   = (L >= 0.0f) ? r : e * r;  // sigmoid(L)

            a_wbce += weit * bce;
            a_int  += p * t * weit;
            a_tot  += (p + t) * weit;
        }
    };

    // ---- Phase A compute: rows 0..31 across both halves (slots 0..61) ----
    do16(half * 16);
    __syncthreads();

    // ---- Phase B scan: rel 62..93 -> slots 62,63,0..29 (live 30..61 kept) ----
    scan_row(62 + wave);
    scan_row(78 + wave);
    __syncthreads();

    // ---- Phase B compute: rows 32..63 across both halves ----
    do16(32 + half * 16);

    // ---- Block reduction ----
#pragma unroll
    for (int off = 32; off > 0; off >>= 1) {
        a_wbce += __shfl_down(a_wbce, off, 64);
        a_int  += __shfl_down(a_int,  off, 64);
        a_tot  += __shfl_down(a_tot,  off, 64);
    }

    if (lane == 0) {
        red[0][wave] = a_wbce; red[1][wave] = a_int; red[2][wave] = a_tot;
    }
    __syncthreads();
    if (threadIdx.x == 0) {
        float w = 0.0f, i2 = 0.0f, t2 = 0.0f;
#pragma unroll
        for (int k = 0; k < 16; ++k) { w += red[0][k]; i2 += red[1][k]; t2 += red[2][k]; }
        pbuf[blockIdx.x]            = w;
        pbuf[NBLK + blockIdx.x]     = i2;
        pbuf[2 * NBLK + blockIdx.x] = t2;
    }
}

// ---------------------------------------------------------------------------
// Finalize: reduce 512 partials per quantity (double accum) + scalar.
// ---------------------------------------------------------------------------
__global__ __launch_bounds__(256) void finalize_kernel(const float* __restrict__ pbuf,
                                                       float* __restrict__ out) {
    const int tidx = threadIdx.x;
    double w = 0.0, i2 = 0.0, t2 = 0.0;
    for (int k = tidx; k < NBLK; k += 256) {
        w  += (double)pbuf[k];
        i2 += (double)pbuf[NBLK + k];
        t2 += (double)pbuf[2 * NBLK + k];
    }
#pragma unroll
    for (int off = 32; off > 0; off >>= 1) {
        w  += __shfl_down(w,  off, 64);
        i2 += __shfl_down(i2, off, 64);
        t2 += __shfl_down(t2, off, 64);
    }
    __shared__ double red[3][4];
    const int wave = tidx >> 6;
    if ((tidx & 63) == 0) { red[0][wave] = w; red[1][wave] = i2; red[2][wave] = t2; }
    __syncthreads();
    if (tidx == 0) {
        double ws = 0.0, is = 0.0, ts = 0.0;
        for (int k = 0; k < 4; ++k) { ws += red[0][k]; is += red[1][k]; ts += red[2][k]; }
        const double wbce   = ws / (double)NTOT;
        const double union_ = ts - is;
        const double wiou   = 1.0 - (is + 1.0) / (union_ + 1.0);
        out[0] = (float)(wbce + wiou);
    }
}

extern "C" void kernel_launch(void* const* d_in, const int* in_sizes, int n_in,
                              void* d_out, int out_size, void* d_ws, size_t ws_size,
                              hipStream_t stream) {
    const float* logits = (const float*)d_in[0];
    const float* targ   = (const float*)d_in[1];
    float* out          = (float*)d_out;
    float* pbuf         = (float*)d_ws;     // 3*NBLK floats (6 KB)

    mega_kernel<<<NBLK, 1024, 0, stream>>>(logits, targ, pbuf);
    finalize_kernel<<<1, 256, 0, stream>>>(pbuf, out);
}

// Round 3
// 147.548 us; speedup vs baseline: 1.4136x; 1.4136x over previous
//
#include <hip/hip_runtime.h>
#include <math.h>

#define BATCH 64
#define HH 512
#define WW 512
#define KRAD 15
#define KSZ 31
#define NTOT ((size_t)BATCH * HH * WW)
#define TILE_Y 64
#define NCHUNK (HH / TILE_Y)            // 8
#define NBLK (BATCH * NCHUNK)           // 512 blocks
#define RING 64                         // fp16 prefix ring rows (64 KB, &63 free)

typedef _Float16 h8 __attribute__((ext_vector_type(8)));

// Wave64 inclusive add-scan via DPP (LLVM AMDGPUAtomicOptimizer sequence).
// Pure VALU: zero LDS-pipe traffic.
__device__ __forceinline__ float dpp_scan_add(float v) {
    int t;
    t = __builtin_amdgcn_update_dpp(0, __float_as_int(v), 0x111, 0xf, 0xf, false); // row_shr:1
    v += __int_as_float(t);
    t = __builtin_amdgcn_update_dpp(0, __float_as_int(v), 0x112, 0xf, 0xf, false); // row_shr:2
    v += __int_as_float(t);
    t = __builtin_amdgcn_update_dpp(0, __float_as_int(v), 0x114, 0xf, 0xf, false); // row_shr:4
    v += __int_as_float(t);
    t = __builtin_amdgcn_update_dpp(0, __float_as_int(v), 0x118, 0xf, 0xf, false); // row_shr:8
    v += __int_as_float(t);
    t = __builtin_amdgcn_update_dpp(0, __float_as_int(v), 0x142, 0xa, 0xf, false); // row_bcast:15 -> rows 1,3
    v += __int_as_float(t);
    t = __builtin_amdgcn_update_dpp(0, __float_as_int(v), 0x143, 0xc, 0xf, false); // row_bcast:31 -> rows 2,3
    v += __int_as_float(t);
    return v;
}

// ---------------------------------------------------------------------------
// TILE_Y=64, 64-row fp16 PREFIX ring, two whole-block phases, ALL 1024
// threads compute (column x = tid&511, vertical half = tid>>9, 16 rows per
// thread per phase). STREAMING body: no per-thread arrays (round-2's vs[16]
// spilled 168 MB of scratch under the 64-VGPR cap). Each strip re-inits its
// 31-row window into 4 scalar partials, then rolls vsum with the loss math
// inlined; #pragma unroll 4 bounds load batching to stay spill-free.
//   scan rel 0..61 -> B -> compute rows 0..31 -> B -> scan rel 62..93
//   (slots 62,63,0..29; live 30..61 untouched) -> B -> compute rows 32..63.
// Ring-slot liveness proven for all (phase, half) strips.
// ---------------------------------------------------------------------------
__global__ __launch_bounds__(1024, 8) void mega_kernel(const float* __restrict__ logits,
                                                       const float* __restrict__ targ,
                                                       float* __restrict__ pbuf) {
    __shared__ _Float16 Pring[RING * WW];   // 64 KB
    __shared__ float red[3][16];

    const int b     = blockIdx.x >> 3;          // batch
    const int chunk = blockIdx.x & (NCHUNK - 1);
    const int y0    = chunk * TILE_Y;

    const int wave = threadIdx.x >> 6;          // 0..15
    const int lane = threadIdx.x & 63;

    // Scan one row (rel = y_abs-(y0-15)): store fp16 PREFIX into slot rel&63.
    // Zero-writes out-of-range rows (zero-pad semantics).
    auto scan_row = [&](int rel) {
        const int y_abs = y0 - KRAD + rel;
        h8 hv = {};
        if (y_abs >= 0 && y_abs < HH) {
            const float4* rp = (const float4*)(targ + ((size_t)b * HH + y_abs) * WW);
            float4 a  = rp[2 * lane];
            float4 b4 = rp[2 * lane + 1];
            float v[8] = {a.x, a.y, a.z, a.w, b4.x, b4.y, b4.z, b4.w};

            float T = 0.0f;
            float P[8];
#pragma unroll
            for (int j = 0; j < 8; ++j) { T += v[j]; P[j] = T; }

            const float incl = dpp_scan_add(T);
            const float excl = incl - T;
#pragma unroll
            for (int j = 0; j < 8; ++j) hv[j] = (_Float16)(P[j] + excl);
        }
        *(h8*)&Pring[(rel & (RING - 1)) * WW + lane * 8] = hv;
    };

    // ---- Phase A scan: rel 0..61 (slots 0..61) ----
#pragma unroll
    for (int i = 0; i < 4; ++i) {
        const int rel = wave + 16 * i;
        if (rel < 62) scan_row(rel);
    }
    __syncthreads();

    // ---- Compute setup: ALL threads. Column x, vertical half. ----
    const int x    = threadIdx.x & (WW - 1);    // 0..511
    const int half = threadIdx.x >> 9;          // 0 or 1
    const float* Tp = targ   + ((size_t)b * HH + y0) * WW + x;
    const float* Lp = logits + ((size_t)b * HH + y0) * WW + x;
    const float inv_ksq = 1.0f / (float)(KSZ * KSZ);
    float a_wbce = 0.0f, a_int = 0.0f, a_tot = 0.0f;

    const int  xa     = (x + KRAD > WW - 1) ? (WW - 1) : (x + KRAD);
    const int  xbc    = (x - KRAD - 1 < 0) ? 0 : (x - KRAD - 1);
    const bool has_lo = (x >= KRAD + 1);

    // H(rel, x) from the prefix ring (2 conflict-free u16 reads)
    auto Hval = [&](int rel) -> float {
        const _Float16* row = &Pring[(rel & (RING - 1)) * WW];
        const float hi = (float)row[xa];
        float lo = (float)row[xbc];
        lo = has_lo ? lo : 0.0f;
        return hi - lo;
    };

    // One 16-row strip starting at absolute row ys. Streaming: scalar
    // partials for init, rolling vsum + inline loss (no arrays -> no spill).
    auto do16 = [&](int ys) {
        float s0 = 0.0f, s1 = 0.0f, s2 = 0.0f, s3 = 0.0f;
#pragma unroll
        for (int r = 0; r < 28; r += 4) {
            s0 += Hval(ys + r);
            s1 += Hval(ys + r + 1);
            s2 += Hval(ys + r + 2);
            s3 += Hval(ys + r + 3);
        }
        s0 += Hval(ys + 28);
        s1 += Hval(ys + 29);
        s2 += Hval(ys + 30);
        float vsum = (s0 + s1) + (s2 + s3);

#pragma unroll 4
        for (int j = 0; j < 16; ++j) {
            const int y = ys + j;
            if (j > 0)
                vsum += Hval(ys + j + 30) - Hval(ys + j - 1);

            const float s = vsum * inv_ksq;
            const float t = Tp[(size_t)y * WW];
            const float L = __builtin_nontemporal_load(Lp + (size_t)y * WW);

            const float weit = 1.0f + 5.0f * fabsf(s - t);
            const float e  = __expf(-fabsf(L));
            const float r  = __builtin_amdgcn_rcpf(1.0f + e);
            const float lg = __logf(1.0f + e);          // softplus(-|L|)
            const float sp  = fmaxf(L, 0.0f) + lg;      // softplus(L)
            const float bce = sp - t * L;
            const float p   = (L >= 0.0f) ? r : e * r;  // sigmoid(L)

            a_wbce += weit * bce;
            a_int  += p * t * weit;
            a_tot  += (p + t) * weit;
        }
    };

    // ---- Phase A compute: rows 0..31 across both halves (slots 0..61) ----
    do16(half * 16);
    __syncthreads();

    // ---- Phase B scan: rel 62..93 -> slots 62,63,0..29 (live 30..61 kept) ----
    scan_row(62 + wave);
    scan_row(78 + wave);
    __syncthreads();

    // ---- Phase B compute: rows 32..63 across both halves ----
    do16(32 + half * 16);

    // ---- Block reduction ----
#pragma unroll
    for (int off = 32; off > 0; off >>= 1) {
        a_wbce += __shfl_down(a_wbce, off, 64);
        a_int  += __shfl_down(a_int,  off, 64);
        a_tot  += __shfl_down(a_tot,  off, 64);
    }

    if (lane == 0) {
        red[0][wave] = a_wbce; red[1][wave] = a_int; red[2][wave] = a_tot;
    }
    __syncthreads();
    if (threadIdx.x == 0) {
        float w = 0.0f, i2 = 0.0f, t2 = 0.0f;
#pragma unroll
        for (int k = 0; k < 16; ++k) { w += red[0][k]; i2 += red[1][k]; t2 += red[2][k]; }
        pbuf[blockIdx.x]            = w;
        pbuf[NBLK + blockIdx.x]     = i2;
        pbuf[2 * NBLK + blockIdx.x] = t2;
    }
}

// ---------------------------------------------------------------------------
// Finalize: reduce 512 partials per quantity (double accum) + scalar.
// ---------------------------------------------------------------------------
__global__ __launch_bounds__(256) void finalize_kernel(const float* __restrict__ pbuf,
                                                       float* __restrict__ out) {
    const int tidx = threadIdx.x;
    double w = 0.0, i2 = 0.0, t2 = 0.0;
    for (int k = tidx; k < NBLK; k += 256) {
        w  += (double)pbuf[k];
        i2 += (double)pbuf[NBLK + k];
        t2 += (double)pbuf[2 * NBLK + k];
    }
#pragma unroll
    for (int off = 32; off > 0; off >>= 1) {
        w  += __shfl_down(w,  off, 64);
        i2 += __shfl_down(i2, off, 64);
        t2 += __shfl_down(t2, off, 64);
    }
    __shared__ double red[3][4];
    const int wave = tidx >> 6;
    if ((tidx & 63) == 0) { red[0][wave] = w; red[1][wave] = i2; red[2][wave] = t2; }
    __syncthreads();
    if (tidx == 0) {
        double ws = 0.0, is = 0.0, ts = 0.0;
        for (int k = 0; k < 4; ++k) { ws += red[0][k]; is += red[1][k]; ts += red[2][k]; }
        const double wbce   = ws / (double)NTOT;
        const double union_ = ts - is;
        const double wiou   = 1.0 - (is + 1.0) / (union_ + 1.0);
        out[0] = (float)(wbce + wiou);
    }
}

extern "C" void kernel_launch(void* const* d_in, const int* in_sizes, int n_in,
                              void* d_out, int out_size, void* d_ws, size_t ws_size,
                              hipStream_t stream) {
    const float* logits = (const float*)d_in[0];
    const float* targ   = (const float*)d_in[1];
    float* out          = (float*)d_out;
    float* pbuf         = (float*)d_ws;     // 3*NBLK floats (6 KB)

    mega_kernel<<<NBLK, 1024, 0, stream>>>(logits, targ, pbuf);
    finalize_kernel<<<1, 256, 0, stream>>>(pbuf, out);
}

// Round 6
// 145.096 us; speedup vs baseline: 1.4375x; 1.0169x over previous
//
#include <hip/hip_runtime.h>
#include <math.h>

#define BATCH 64
#define HH 512
#define WW 512
#define KRAD 15
#define KSZ 31
#define NTOT ((size_t)BATCH * HH * WW)
#define TILE_Y 64
#define NCHUNK (HH / TILE_Y)            // 8
#define NBLK (BATCH * NCHUNK)           // 512 blocks
#define RING 64                         // fp16 ring rows (64 KB, &63 free)

typedef _Float16 h8 __attribute__((ext_vector_type(8)));

// Wave64 inclusive add-scan via DPP (LLVM AMDGPUAtomicOptimizer sequence).
__device__ __forceinline__ float dpp_scan_add(float v) {
    int t;
    t = __builtin_amdgcn_update_dpp(0, __float_as_int(v), 0x111, 0xf, 0xf, false); // row_shr:1
    v += __int_as_float(t);
    t = __builtin_amdgcn_update_dpp(0, __float_as_int(v), 0x112, 0xf, 0xf, false); // row_shr:2
    v += __int_as_float(t);
    t = __builtin_amdgcn_update_dpp(0, __float_as_int(v), 0x114, 0xf, 0xf, false); // row_shr:4
    v += __int_as_float(t);
    t = __builtin_amdgcn_update_dpp(0, __float_as_int(v), 0x118, 0xf, 0xf, false); // row_shr:8
    v += __int_as_float(t);
    t = __builtin_amdgcn_update_dpp(0, __float_as_int(v), 0x142, 0xa, 0xf, false); // row_bcast:15 -> rows 1,3
    v += __int_as_float(t);
    t = __builtin_amdgcn_update_dpp(0, __float_as_int(v), 0x143, 0xc, 0xf, false); // row_bcast:31 -> rows 2,3
    v += __int_as_float(t);
    return v;
}

// ---------------------------------------------------------------------------
// TILE_Y=64, 64-row fp16 ring storing the horizontal WINDOWED SUM H (not the
// prefix P). scan_row computes P in registers, writes it to the slot, then
// the same wave re-reads three shifted aligned vectors of its own row
// (DS-pipe per-wave FIFO + explicit lgkmcnt(0) makes write->read safe), forms
//   H[x] = P[min(x+15,511)] - (x>=16 ? P[x-16] : 0)
// and overwrites the slot with H. The hot compute phase then needs ONE
// ds_read_u16 per Hval (was 2) and no clamp/has_lo selects.
// All 1024 threads compute: column x = tid&511, half = tid>>9, 16 rows per
// thread per phase, streaming body (no arrays -> no scratch spill).
//   scan rel 0..61 -> B -> compute rows 0..31 -> B -> scan rel 62..93
//   (slots 62,63,0..29; live 30..61 untouched) -> B -> compute rows 32..63.
// ---------------------------------------------------------------------------
__global__ __launch_bounds__(1024, 8) void mega_kernel(const float* __restrict__ logits,
                                                       const float* __restrict__ targ,
                                                       float* __restrict__ pbuf) {
    __shared__ _Float16 Hring[RING * WW];   // 64 KB
    __shared__ float red[3][16];

    const int b     = blockIdx.x >> 3;          // batch
    const int chunk = blockIdx.x & (NCHUNK - 1);
    const int y0    = chunk * TILE_Y;

    const int wave = threadIdx.x >> 6;          // 0..15
    const int lane = threadIdx.x & 63;

    // Scan one row (rel = y_abs-(y0-15)): prefix -> round-trip -> windowed H.
    auto scan_row = [&](int rel) {
        const int slot = rel & (RING - 1);
        _Float16* row = &Hring[slot * WW];
        const int y_abs = y0 - KRAD + rel;

        if (y_abs < 0 || y_abs >= HH) {          // zero-pad rows (wave-uniform)
            *(h8*)&row[lane * 8] = (h8){};
            return;
        }

        const float4* rp = (const float4*)(targ + ((size_t)b * HH + y_abs) * WW);
        float4 a  = rp[2 * lane];
        float4 b4 = rp[2 * lane + 1];
        float v[8] = {a.x, a.y, a.z, a.w, b4.x, b4.y, b4.z, b4.w};

        float T = 0.0f;
        float P[8];
#pragma unroll
        for (int j = 0; j < 8; ++j) { T += v[j]; P[j] = T; }

        const float incl = dpp_scan_add(T);
        const float excl = incl - T;
        h8 hv;
#pragma unroll
        for (int j = 0; j < 8; ++j) hv[j] = (_Float16)(P[j] + excl);
        *(h8*)&row[lane * 8] = hv;               // publish P

        const float Ptot = __shfl(incl, 63);     // P[511] (row total)

        // ensure P store retired before shifted reads (and pin order)
        asm volatile("s_waitcnt lgkmcnt(0)" ::: "memory");

        // shifted aligned reads of our own row
        h8 lo8 = (h8){};
        if (lane >= 2) lo8 = *(const h8*)&row[lane * 8 - 16];   // P[x-16..x-9]
        const int eA = (lane * 8 + 8  <= WW - 8) ? (lane * 8 + 8)  : (WW - 8);
        const int eB = (lane * 8 + 16 <= WW - 8) ? (lane * 8 + 16) : (WW - 8);
        const h8 A8 = *(const h8*)&row[eA];      // P[xe+8 .. xe+15]
        const h8 B8 = *(const h8*)&row[eB];      // P[xe+16 .. xe+23]

        const int xe = lane * 8;
        float Hv[8];
        {
            const float hi0 = (xe > 496) ? Ptot : (float)A8[7];   // P[xe+15]
            Hv[0] = hi0 - (float)lo8[0];
#pragma unroll
            for (int j = 1; j < 8; ++j) {
                const float hij = (xe + j > 496) ? Ptot : (float)B8[j - 1]; // P[xe+j+15]
                Hv[j] = hij - (float)lo8[j];
            }
        }
        h8 hw;
#pragma unroll
        for (int j = 0; j < 8; ++j) hw[j] = (_Float16)Hv[j];
        *(h8*)&row[lane * 8] = hw;               // overwrite slot with H
    };

    // ---- Phase A scan: rel 0..61 (slots 0..61) ----
#pragma unroll
    for (int i = 0; i < 4; ++i) {
        const int rel = wave + 16 * i;
        if (rel < 62) scan_row(rel);
    }
    __syncthreads();

    // ---- Compute setup: ALL threads. Column x, vertical half. ----
    const int x    = threadIdx.x & (WW - 1);    // 0..511
    const int half = threadIdx.x >> 9;          // 0 or 1
    const _Float16* colH = &Hring[x];
    const float* Tp = targ   + ((size_t)b * HH + y0) * WW + x;
    const float* Lp = logits + ((size_t)b * HH + y0) * WW + x;
    const float inv_ksq = 1.0f / (float)(KSZ * KSZ);
    float a_wbce = 0.0f, a_int = 0.0f, a_tot = 0.0f;

    // H(rel, x): ONE conflict-free ds_read_u16
    auto Hval = [&](int rel) -> float {
        return (float)colH[(rel & (RING - 1)) * WW];
    };

    // One 16-row strip starting at absolute row ys. Streaming: scalar
    // partials for init, rolling vsum + inline loss (no arrays -> no spill).
    auto do16 = [&](int ys) {
        float s0 = 0.0f, s1 = 0.0f, s2 = 0.0f, s3 = 0.0f;
#pragma unroll
        for (int r = 0; r < 28; r += 4) {
            s0 += Hval(ys + r);
            s1 += Hval(ys + r + 1);
            s2 += Hval(ys + r + 2);
            s3 += Hval(ys + r + 3);
        }
        s0 += Hval(ys + 28);
        s1 += Hval(ys + 29);
        s2 += Hval(ys + 30);
        float vsum = (s0 + s1) + (s2 + s3);

#pragma unroll 4
        for (int j = 0; j < 16; ++j) {
            const int y = ys + j;
            if (j > 0)
                vsum += Hval(ys + j + 30) - Hval(ys + j - 1);

            const float s = vsum * inv_ksq;
            const float t = Tp[(size_t)y * WW];
            const float L = __builtin_nontemporal_load(Lp + (size_t)y * WW);

            const float weit = 1.0f + 5.0f * fabsf(s - t);
            const float e  = __expf(-fabsf(L));
            const float r  = __builtin_amdgcn_rcpf(1.0f + e);
            const float lg = __logf(1.0f + e);          // softplus(-|L|)
            const float sp  = fmaxf(L, 0.0f) + lg;      // softplus(L)
            const float bce = sp - t * L;
            const float p   = (L >= 0.0f) ? r : e * r;  // sigmoid(L)

            a_wbce += weit * bce;
            a_int  += p * t * weit;
            a_tot  += (p + t) * weit;
        }
    };

    // ---- Phase A compute: rows 0..31 across both halves (slots 0..61) ----
    do16(half * 16);
    __syncthreads();

    // ---- Phase B scan: rel 62..93 -> slots 62,63,0..29 (live 30..61 kept) ----
    scan_row(62 + wave);
    scan_row(78 + wave);
    __syncthreads();

    // ---- Phase B compute: rows 32..63 across both halves ----
    do16(32 + half * 16);

    // ---- Block reduction ----
#pragma unroll
    for (int off = 32; off > 0; off >>= 1) {
        a_wbce += __shfl_down(a_wbce, off, 64);
        a_int  += __shfl_down(a_int,  off, 64);
        a_tot  += __shfl_down(a_tot,  off, 64);
    }

    if (lane == 0) {
        red[0][wave] = a_wbce; red[1][wave] = a_int; red[2][wave] = a_tot;
    }
    __syncthreads();
    if (threadIdx.x == 0) {
        float w = 0.0f, i2 = 0.0f, t2 = 0.0f;
#pragma unroll
        for (int k = 0; k < 16; ++k) { w += red[0][k]; i2 += red[1][k]; t2 += red[2][k]; }
        pbuf[blockIdx.x]            = w;
        pbuf[NBLK + blockIdx.x]     = i2;
        pbuf[2 * NBLK + blockIdx.x] = t2;
    }
}

// ---------------------------------------------------------------------------
// Finalize: reduce 512 partials per quantity (double accum) + scalar.
// ---------------------------------------------------------------------------
__global__ __launch_bounds__(256) void finalize_kernel(const float* __restrict__ pbuf,
                                                       float* __restrict__ out) {
    const int tidx = threadIdx.x;
    double w = 0.0, i2 = 0.0, t2 = 0.0;
    for (int k = tidx; k < NBLK; k += 256) {
        w  += (double)pbuf[k];
        i2 += (double)pbuf[NBLK + k];
        t2 += (double)pbuf[2 * NBLK + k];
    }
#pragma unroll
    for (int off = 32; off > 0; off >>= 1) {
        w  += __shfl_down(w,  off, 64);
        i2 += __shfl_down(i2, off, 64);
        t2 += __shfl_down(t2, off, 64);
    }
    __shared__ double red[3][4];
    const int wave = tidx >> 6;
    if ((tidx & 63) == 0) { red[0][wave] = w; red[1][wave] = i2; red[2][wave] = t2; }
    __syncthreads();
    if (tidx == 0) {
        double ws = 0.0, is = 0.0, ts = 0.0;
        for (int k = 0; k < 4; ++k) { ws += red[0][k]; is += red[1][k]; ts += red[2][k]; }
        const double wbce   = ws / (double)NTOT;
        const double union_ = ts - is;
        const double wiou   = 1.0 - (is + 1.0) / (union_ + 1.0);
        out[0] = (float)(wbce + wiou);
    }
}

extern "C" void kernel_launch(void* const* d_in, const int* in_sizes, int n_in,
                              void* d_out, int out_size, void* d_ws, size_t ws_size,
                              hipStream_t stream) {
    const float* logits = (const float*)d_in[0];
    const float* targ   = (const float*)d_in[1];
    float* out          = (float*)d_out;
    float* pbuf         = (float*)d_ws;     // 3*NBLK floats (6 KB)

    mega_kernel<<<NBLK, 1024, 0, stream>>>(logits, targ, pbuf);
    finalize_kernel<<<1, 256, 0, stream>>>(pbuf, out);
}